// Round 7
// baseline (176.975 us; speedup 1.0000x reference)
//
#include <hip/hip_runtime.h>

typedef __attribute__((ext_vector_type(8))) short bf16x8;
typedef __attribute__((ext_vector_type(16))) float f32x16;

#define MFMA32 __builtin_amdgcn_mfma_f32_32x32x16_bf16

__device__ __forceinline__ unsigned short bf16r(float f){
  unsigned u = __builtin_bit_cast(unsigned, f);
  unsigned r = (u + 0x7FFFu + ((u >> 16) & 1u)) >> 16;
  return (unsigned short)r;
}
__device__ __forceinline__ unsigned bfpack2(float a, float b){
  unsigned ua = __builtin_bit_cast(unsigned, a);
  unsigned ub = __builtin_bit_cast(unsigned, b);
  unsigned ra = (ua + 0x7FFFu + ((ua >> 16) & 1u)) >> 16;
  unsigned rb = (ub + 0x7FFFu + ((ub >> 16) & 1u)) & 0xFFFF0000u;
  return (ra & 0xFFFFu) | rb;
}
__device__ __forceinline__ float bf2f(unsigned short h){
  unsigned u = ((unsigned)h) << 16;
  return __builtin_bit_cast(float, u);
}
__device__ __forceinline__ unsigned cvtpk_bf16(float a, float b){
  unsigned r;
  asm("v_cvt_pk_bf16_f32 %0, %1, %2" : "=v"(r) : "v"(a), "v"(b));
  return r;
}
__device__ __forceinline__ void permswap(unsigned &x, unsigned &y){
  asm volatile("v_permlane32_swap_b32 %0, %1" : "+v"(x), "+v"(y));
}
__device__ __forceinline__ float fexp2(float x){     // raw v_exp_f32 (2^x)
  float r; asm("v_exp_f32 %0, %1" : "=v"(r) : "v"(x)); return r;
}

// ---------------- weight transpose: W[k][n] f32 -> WT[n][k] bf16 (512x512, 4 mats)
__global__ __launch_bounds__(256) void wt_kernel(
    const float* __restrict__ W0, const float* __restrict__ W1,
    const float* __restrict__ W2, const float* __restrict__ W3,
    unsigned short* __restrict__ T0, unsigned short* __restrict__ T1,
    unsigned short* __restrict__ T2, unsigned short* __restrict__ T3)
{
  int z = blockIdx.z;
  const float* W = z==0?W0 : z==1?W1 : z==2?W2 : W3;
  unsigned short* T = z==0?T0 : z==1?T1 : z==2?T2 : T3;
  __shared__ float tile[64][68];
  int kb0 = blockIdx.x*64, nb0 = blockIdx.y*64;
  int tid = threadIdx.x;
#pragma unroll
  for (int i=0;i<4;++i){
    int c = tid + i*256; int r = c>>4, cc = (c&15)*4;
    *(float4*)&tile[r][cc] = *(const float4*)&W[(kb0+r)*512 + nb0 + cc];
  }
  __syncthreads();
#pragma unroll
  for (int i=0;i<4;++i){
    int c = tid + i*256; int o = c*4; int n = o>>6, kk = o&63;
    ushort4 pk;
    pk.x = bf16r(tile[kk+0][n]); pk.y = bf16r(tile[kk+1][n]);
    pk.z = bf16r(tile[kk+2][n]); pk.w = bf16r(tile[kk+3][n]);
    *(ushort4*)&T[(nb0+n)*512 + kb0 + kk] = pk;
  }
}

// ---------------- fused QKV projection. grid (64,4,3).
// z=0: q = Q@Wq+bq           -> qbuf (bf16)
// z=1: k = (K@Wk+bk)*scale_m -> kbuf (bf16), scale_m = log2e/(sqrt(512)*temp[m])
// z=2: v = K@Wv+bv           -> vt (bf16, tile-major [b][kt32][d][kk32]) via LDS transpose
__global__ __launch_bounds__(256,2) void qkv_kernel(
    const float* __restrict__ Qin, const float* __restrict__ Kin,
    const unsigned short* __restrict__ WqT, const unsigned short* __restrict__ WkT,
    const unsigned short* __restrict__ WvT,
    const float* __restrict__ bq, const float* __restrict__ bk,
    const float* __restrict__ bv, const float* __restrict__ temp,
    unsigned short* __restrict__ qbuf, unsigned short* __restrict__ kbuf,
    unsigned short* __restrict__ vt)
{
  const float RS2K = 0.044194173824159216f * 1.4426950408889634f;
  __shared__ short SM[128*144];                    // As|Bs, reused as Lt[128][144]
  short (*As)[72] = (short(*)[72])SM;
  short (*Bs)[72] = (short(*)[72])(SM + 128*72);
  int z = blockIdx.z;
  const float* A = (z==0) ? Qin : Kin;
  const unsigned short* BT = z==0 ? WqT : (z==1 ? WkT : WvT);
  const float* bias = z==0 ? bq : (z==1 ? bk : bv);
  int m0 = blockIdx.x*128, n0 = blockIdx.y*128;
  int tid = threadIdx.x;
  int lane = tid & 63, w = tid >> 6, l5 = lane & 31, hi = lane >> 5;
  int wr = w >> 1, wc = w & 1;
  f32x16 acc00, acc01, acc10, acc11;
#pragma unroll
  for (int i=0;i<16;++i){ acc00[i]=0.f; acc01[i]=0.f; acc10[i]=0.f; acc11[i]=0.f; }

  for (int kt=0; kt<8; ++kt){
    int k0 = kt*64;
    __syncthreads();
#pragma unroll
    for (int i=0;i<4;++i){
      int c = tid + i*256; int r = c>>3, cc = (c&7)*8;
      const float* src = &A[(m0+r)*512 + k0 + cc];
      float4 v0 = *(const float4*)src;
      float4 v1 = *(const float4*)(src+4);
      uint4 pk;
      pk.x = bfpack2(v0.x, v0.y); pk.y = bfpack2(v0.z, v0.w);
      pk.z = bfpack2(v1.x, v1.y); pk.w = bfpack2(v1.z, v1.w);
      *(uint4*)&As[r][cc] = pk;
    }
#pragma unroll
    for (int i=0;i<4;++i){
      int c = tid + i*256; int r = c>>3, cc = (c&7)*8;
      *(uint4*)&Bs[r][cc] = *(const uint4*)&BT[(n0+r)*512 + k0 + cc];
    }
    __syncthreads();
#pragma unroll
    for (int ks=0; ks<4; ++ks){
      bf16x8 a0 = *(const bf16x8*)&As[wr*64 + l5     ][ks*16 + hi*8];
      bf16x8 a1 = *(const bf16x8*)&As[wr*64 + 32 + l5][ks*16 + hi*8];
      bf16x8 b0 = *(const bf16x8*)&Bs[wc*64 + l5     ][ks*16 + hi*8];
      bf16x8 b1 = *(const bf16x8*)&Bs[wc*64 + 32 + l5][ks*16 + hi*8];
      acc00 = MFMA32(a0, b0, acc00, 0,0,0);
      acc01 = MFMA32(a0, b1, acc01, 0,0,0);
      acc10 = MFMA32(a1, b0, acc10, 0,0,0);
      acc11 = MFMA32(a1, b1, acc11, 0,0,0);
    }
  }

  if (z <= 1){
    unsigned short* Cout = (z==0) ? qbuf : kbuf;
#pragma unroll
    for (int mt=0; mt<2; ++mt){
      float sc[16];
      if (z==1){
        int mb = m0 + wr*64 + mt*32 + 4*hi;
#pragma unroll
        for (int qd=0; qd<4; ++qd)
#pragma unroll
        for (int j=0; j<4; ++j)
          sc[qd*4+j] = RS2K*__builtin_amdgcn_rcpf(temp[mb + qd*8 + j]);
      }
#pragma unroll
      for (int nt=0; nt<2; ++nt){
        const f32x16& acc = mt==0 ? (nt==0?acc00:acc01) : (nt==0?acc10:acc11);
        int n = n0 + wc*64 + nt*32 + l5;
        float bn = bias[n];
#pragma unroll
        for (int r=0;r<16;++r){
          int m = m0 + wr*64 + mt*32 + (r&3) + 8*(r>>2) + 4*hi;
          float v = acc[r] + bn;
          if (z==1) v *= sc[r];
          Cout[m*512 + n] = bf16r(v);
        }
      }
    }
  } else {
    // ---- V: transpose via LDS, store tile-major
    __syncthreads();                       // done reading As/Bs
    short* Lt = SM;                        // [128 n][144 m-stride]
#pragma unroll
    for (int mt=0; mt<2; ++mt)
#pragma unroll
    for (int nt=0; nt<2; ++nt){
      const f32x16& acc = mt==0 ? (nt==0?acc00:acc01) : (nt==0?acc10:acc11);
      int n = wc*64 + nt*32 + l5;
      float bn = bias[n0 + n];
#pragma unroll
      for (int qd=0; qd<4; ++qd){
        int mloc = wr*64 + mt*32 + qd*8 + 4*hi;
        uint2 pk;
        pk.x = bfpack2(acc[qd*4+0]+bn, acc[qd*4+1]+bn);
        pk.y = bfpack2(acc[qd*4+2]+bn, acc[qd*4+3]+bn);
        *(uint2*)&Lt[n*144 + mloc] = pk;
      }
    }
    __syncthreads();
    int b = m0 >> 11;
    int ktb = (m0 & 2047) >> 5;
#pragma unroll
    for (int pass=0; pass<2; ++pass){
      int d = (tid>>2) + pass*64;
      int kk0 = (tid&3)*8;
#pragma unroll
      for (int kt=0; kt<4; ++kt){
        uint4 v = *(const uint4*)&Lt[d*144 + kt*32 + kk0];
        *(uint4*)&vt[(size_t)((b*64 + ktb + kt)*512 + n0 + d)*32 + kk0] = v;
      }
    }
  }
}

// ---------------- GEMM (O-projection): C = relu(A@W + bias) + resid, A bf16
__global__ __launch_bounds__(256,2) void gemm_o_kernel(
    const unsigned short* __restrict__ A, const unsigned short* __restrict__ BT,
    const float* __restrict__ bias, float* __restrict__ Cout,
    const unsigned short* __restrict__ resid)
{
  __shared__ short As[128][72];
  __shared__ short Bs[128][72];
  int m0 = blockIdx.x*128, n0 = blockIdx.y*128;
  int tid = threadIdx.x;
  int lane = tid & 63, w = tid >> 6, l5 = lane & 31, hi = lane >> 5;
  int wr = w >> 1, wc = w & 1;
  f32x16 acc00, acc01, acc10, acc11;
#pragma unroll
  for (int i=0;i<16;++i){ acc00[i]=0.f; acc01[i]=0.f; acc10[i]=0.f; acc11[i]=0.f; }

  for (int kt=0; kt<8; ++kt){
    int k0 = kt*64;
    __syncthreads();
#pragma unroll
    for (int i=0;i<4;++i){
      int c = tid + i*256; int r = c>>3, cc = (c&7)*8;
      *(uint4*)&As[r][cc] = *(const uint4*)&A[(m0+r)*512 + k0 + cc];
    }
#pragma unroll
    for (int i=0;i<4;++i){
      int c = tid + i*256; int r = c>>3, cc = (c&7)*8;
      *(uint4*)&Bs[r][cc] = *(const uint4*)&BT[(n0+r)*512 + k0 + cc];
    }
    __syncthreads();
#pragma unroll
    for (int ks=0; ks<4; ++ks){
      bf16x8 a0 = *(const bf16x8*)&As[wr*64 + l5     ][ks*16 + hi*8];
      bf16x8 a1 = *(const bf16x8*)&As[wr*64 + 32 + l5][ks*16 + hi*8];
      bf16x8 b0 = *(const bf16x8*)&Bs[wc*64 + l5     ][ks*16 + hi*8];
      bf16x8 b1 = *(const bf16x8*)&Bs[wc*64 + 32 + l5][ks*16 + hi*8];
      acc00 = MFMA32(a0, b0, acc00, 0,0,0);
      acc01 = MFMA32(a0, b1, acc01, 0,0,0);
      acc10 = MFMA32(a1, b0, acc10, 0,0,0);
      acc11 = MFMA32(a1, b1, acc11, 0,0,0);
    }
  }
#pragma unroll
  for (int mt=0; mt<2; ++mt){
#pragma unroll
    for (int nt=0; nt<2; ++nt){
      const f32x16& acc = mt==0 ? (nt==0?acc00:acc01) : (nt==0?acc10:acc11);
      int n = n0 + wc*64 + nt*32 + l5;
      float bn = bias[n];
#pragma unroll
      for (int r=0;r<16;++r){
        int m = m0 + wr*64 + mt*32 + (r&3) + 8*(r>>2) + 4*hi;
        float v = acc[r] + bn;
        Cout[m*512 + n] = fmaxf(v, 0.f) + bf2f(resid[m*512 + n]);
      }
    }
  }
}

// ---------------- flash attention: barrier-free, LDS-free, per-wave direct fragments.
// grid 512: (b, s, qt 32, hv). 256 thr = 4 independent waves = 4 heads.
// Each wave: 64 q-rows (2 subtiles) x its 64 channels, k-split half (1024 keys).
__global__ __launch_bounds__(256,2) void attn_kernel(
    const unsigned short* __restrict__ qb, const unsigned short* __restrict__ kb,
    const unsigned short* __restrict__ vt, const int* __restrict__ mask,
    unsigned short* __restrict__ Op, float* __restrict__ lbuf)
{
  int bid = blockIdx.x;
  int swz = (bid & 7)*64 + (bid >> 3);    // XCD-chunked: each XCD owns one (b,s)
  int hv = swz & 1;
  int qt = (swz >> 1) & 31;
  int g  = swz >> 6;
  int b  = g >> 1, s = g & 1;
  int q0 = qt * 64;

  int tid = threadIdx.x;
  int lane = tid & 63, w = tid >> 6, l5 = lane & 31, hi = lane >> 5;
  int hcho = hv*256 + w*64;               // this wave's channel base

  // Q fragments for both subtiles (B-operand of S^T), hoisted
  bf16x8 qlo0,qlo1,qlo2,qlo3, qhi0,qhi1,qhi2,qhi3;
  {
    const unsigned short* qp = qb + (size_t)(b*2048 + q0 + l5)*512 + hcho + hi*8;
    qlo0 = *(const bf16x8*)(qp);
    qlo1 = *(const bf16x8*)(qp + 16);
    qlo2 = *(const bf16x8*)(qp + 32);
    qlo3 = *(const bf16x8*)(qp + 48);
    qp += (size_t)32*512;
    qhi0 = *(const bf16x8*)(qp);
    qhi1 = *(const bf16x8*)(qp + 16);
    qhi2 = *(const bf16x8*)(qp + 32);
    qhi3 = *(const bf16x8*)(qp + 48);
  }

  f32x16 oL0, oL1, oH0, oH1;
#pragma unroll
  for (int i=0;i<16;++i){ oL0[i]=0.f; oL1[i]=0.f; oH0[i]=0.f; oH1[i]=0.f; }
  float lsumL = 0.f, lsumH = 0.f;

  const int kbeg = s*32, kend = s*32 + 32;
  const unsigned short* kp0 = kb + (size_t)(b*2048 + l5)*512 + hcho + hi*8;   // + kt*32*512
  const unsigned short* vp0 = vt + ((size_t)(b*64)*512 + hcho + l5)*32 + hi*8; // + kt*512*32
  const int* mpl0 = mask + (size_t)(b*2048 + q0 + l5)*2048 + 4*hi;            // + kt*32
  const int* mph0 = mpl0 + (size_t)32*2048;

  uint4 kA,kB,kC,kD, vA,vB,vC,vD;
  int4 mL0,mL1,mL2,mL3, mH0,mH1,mH2,mH3;
  {
    const unsigned short* kp = kp0 + (size_t)kbeg*32*512;
    kA = *(const uint4*)(kp);      kB = *(const uint4*)(kp + 16);
    kC = *(const uint4*)(kp + 32); kD = *(const uint4*)(kp + 48);
    const unsigned short* vp = vp0 + (size_t)kbeg*512*32;
    vA = *(const uint4*)(vp);        vB = *(const uint4*)(vp + 16);
    vC = *(const uint4*)(vp + 1024); vD = *(const uint4*)(vp + 1040);
    const int* ml = mpl0 + kbeg*32;
    mL0 = *(const int4*)(ml);      mL1 = *(const int4*)(ml + 8);
    mL2 = *(const int4*)(ml + 16); mL3 = *(const int4*)(ml + 24);
    const int* mh = mph0 + kbeg*32;
    mH0 = *(const int4*)(mh);      mH1 = *(const int4*)(mh + 8);
    mH2 = *(const int4*)(mh + 16); mH3 = *(const int4*)(mh + 24);
  }

  for (int kt=kbeg; kt<kend; ++kt){
    bool more = (kt+1 < kend);
    // ---- S^T lo: 4 MFMA
    f32x16 sA;
#pragma unroll
    for (int i=0;i<16;++i) sA[i] = 0.f;
    __builtin_amdgcn_s_setprio(1);
    sA = MFMA32(__builtin_bit_cast(bf16x8,kA), qlo0, sA, 0,0,0);
    sA = MFMA32(__builtin_bit_cast(bf16x8,kB), qlo1, sA, 0,0,0);
    sA = MFMA32(__builtin_bit_cast(bf16x8,kC), qlo2, sA, 0,0,0);
    sA = MFMA32(__builtin_bit_cast(bf16x8,kD), qlo3, sA, 0,0,0);
    __builtin_amdgcn_s_setprio(0);
    // ---- exp/pack lo (consumes mL*)
    float p0,p1,p2,p3,p4,p5,p6,p7,p8,p9,pa,pb,pc,pd,pe,pf;
    p0 = fexp2(mL0.x ? sA[0]  : -1.44269504e9f);
    p1 = fexp2(mL0.y ? sA[1]  : -1.44269504e9f);
    p2 = fexp2(mL0.z ? sA[2]  : -1.44269504e9f);
    p3 = fexp2(mL0.w ? sA[3]  : -1.44269504e9f);
    p4 = fexp2(mL1.x ? sA[4]  : -1.44269504e9f);
    p5 = fexp2(mL1.y ? sA[5]  : -1.44269504e9f);
    p6 = fexp2(mL1.z ? sA[6]  : -1.44269504e9f);
    p7 = fexp2(mL1.w ? sA[7]  : -1.44269504e9f);
    p8 = fexp2(mL2.x ? sA[8]  : -1.44269504e9f);
    p9 = fexp2(mL2.y ? sA[9]  : -1.44269504e9f);
    pa = fexp2(mL2.z ? sA[10] : -1.44269504e9f);
    pb = fexp2(mL2.w ? sA[11] : -1.44269504e9f);
    pc = fexp2(mL3.x ? sA[12] : -1.44269504e9f);
    pd = fexp2(mL3.y ? sA[13] : -1.44269504e9f);
    pe = fexp2(mL3.z ? sA[14] : -1.44269504e9f);
    pf = fexp2(mL3.w ? sA[15] : -1.44269504e9f);
    lsumL += (((p0+p1)+(p2+p3)) + ((p4+p5)+(p6+p7))) +
             (((p8+p9)+(pa+pb)) + ((pc+pd)+(pe+pf)));
    // ---- issue mask-lo loads for t+1
    if (more){
      const int* ml = mpl0 + (kt+1)*32;
      mL0 = *(const int4*)(ml);      mL1 = *(const int4*)(ml + 8);
      mL2 = *(const int4*)(ml + 16); mL3 = *(const int4*)(ml + 24);
    }
    unsigned uL0 = cvtpk_bf16(p0, p1);
    unsigned uL1 = cvtpk_bf16(p2, p3);
    unsigned uL2 = cvtpk_bf16(p4, p5);
    unsigned uL3 = cvtpk_bf16(p6, p7);
    permswap(uL0, uL2); permswap(uL1, uL3);
    unsigned uL4 = cvtpk_bf16(p8, p9);
    unsigned uL5 = cvtpk_bf16(pa, pb);
    unsigned uL6 = cvtpk_bf16(pc, pd);
    unsigned uL7 = cvtpk_bf16(pe, pf);
    permswap(uL4, uL6); permswap(uL5, uL7);
    uint4 w0; w0.x=uL0; w0.y=uL1; w0.z=uL2; w0.w=uL3;
    uint4 w1; w1.x=uL4; w1.y=uL5; w1.z=uL6; w1.w=uL7;
    bf16x8 paL0 = __builtin_bit_cast(bf16x8, w0);
    bf16x8 paL1 = __builtin_bit_cast(bf16x8, w1);

    // ---- S^T hi: 4 MFMA (K dead after)
#pragma unroll
    for (int i=0;i<16;++i) sA[i] = 0.f;
    __builtin_amdgcn_s_setprio(1);
    sA = MFMA32(__builtin_bit_cast(bf16x8,kA), qhi0, sA, 0,0,0);
    sA = MFMA32(__builtin_bit_cast(bf16x8,kB), qhi1, sA, 0,0,0);
    sA = MFMA32(__builtin_bit_cast(bf16x8,kC), qhi2, sA, 0,0,0);
    sA = MFMA32(__builtin_bit_cast(bf16x8,kD), qhi3, sA, 0,0,0);
    __builtin_amdgcn_s_setprio(0);
    // ---- issue K loads for t+1
    if (more){
      const unsigned short* kp = kp0 + (size_t)(kt+1)*32*512;
      kA = *(const uint4*)(kp);      kB = *(const uint4*)(kp + 16);
      kC = *(const uint4*)(kp + 32); kD = *(const uint4*)(kp + 48);
    }
    // ---- exp/pack hi (consumes mH*)
    p0 = fexp2(mH0.x ? sA[0]  : -1.44269504e9f);
    p1 = fexp2(mH0.y ? sA[1]  : -1.44269504e9f);
    p2 = fexp2(mH0.z ? sA[2]  : -1.44269504e9f);
    p3 = fexp2(mH0.w ? sA[3]  : -1.44269504e9f);
    p4 = fexp2(mH1.x ? sA[4]  : -1.44269504e9f);
    p5 = fexp2(mH1.y ? sA[5]  : -1.44269504e9f);
    p6 = fexp2(mH1.z ? sA[6]  : -1.44269504e9f);
    p7 = fexp2(mH1.w ? sA[7]  : -1.44269504e9f);
    p8 = fexp2(mH2.x ? sA[8]  : -1.44269504e9f);
    p9 = fexp2(mH2.y ? sA[9]  : -1.44269504e9f);
    pa = fexp2(mH2.z ? sA[10] : -1.44269504e9f);
    pb = fexp2(mH2.w ? sA[11] : -1.44269504e9f);
    pc = fexp2(mH3.x ? sA[12] : -1.44269504e9f);
    pd = fexp2(mH3.y ? sA[13] : -1.44269504e9f);
    pe = fexp2(mH3.z ? sA[14] : -1.44269504e9f);
    pf = fexp2(mH3.w ? sA[15] : -1.44269504e9f);
    lsumH += (((p0+p1)+(p2+p3)) + ((p4+p5)+(p6+p7))) +
             (((p8+p9)+(pa+pb)) + ((pc+pd)+(pe+pf)));
    // ---- issue mask-hi loads for t+1
    if (more){
      const int* mh = mph0 + (kt+1)*32;
      mH0 = *(const int4*)(mh);      mH1 = *(const int4*)(mh + 8);
      mH2 = *(const int4*)(mh + 16); mH3 = *(const int4*)(mh + 24);
    }
    unsigned uH0 = cvtpk_bf16(p0, p1);
    unsigned uH1 = cvtpk_bf16(p2, p3);
    unsigned uH2 = cvtpk_bf16(p4, p5);
    unsigned uH3 = cvtpk_bf16(p6, p7);
    permswap(uH0, uH2); permswap(uH1, uH3);
    unsigned uH4 = cvtpk_bf16(p8, p9);
    unsigned uH5 = cvtpk_bf16(pa, pb);
    unsigned uH6 = cvtpk_bf16(pc, pd);
    unsigned uH7 = cvtpk_bf16(pe, pf);
    permswap(uH4, uH6); permswap(uH5, uH7);
    uint4 w2; w2.x=uH0; w2.y=uH1; w2.z=uH2; w2.w=uH3;
    uint4 w3; w3.x=uH4; w3.y=uH5; w3.z=uH6; w3.w=uH7;
    bf16x8 paH0 = __builtin_bit_cast(bf16x8, w2);
    bf16x8 paH1 = __builtin_bit_cast(bf16x8, w3);

    // ---- PV: 8 MFMA (V dead after)
    bf16x8 v00 = __builtin_bit_cast(bf16x8, vA);
    bf16x8 v01 = __builtin_bit_cast(bf16x8, vB);
    bf16x8 v10 = __builtin_bit_cast(bf16x8, vC);
    bf16x8 v11 = __builtin_bit_cast(bf16x8, vD);
    __builtin_amdgcn_s_setprio(1);
    oL0 = MFMA32(paL0, v00, oL0, 0,0,0);
    oL0 = MFMA32(paL1, v01, oL0, 0,0,0);
    oL1 = MFMA32(paL0, v10, oL1, 0,0,0);
    oL1 = MFMA32(paL1, v11, oL1, 0,0,0);
    oH0 = MFMA32(paH0, v00, oH0, 0,0,0);
    oH0 = MFMA32(paH1, v01, oH0, 0,0,0);
    oH1 = MFMA32(paH0, v10, oH1, 0,0,0);
    oH1 = MFMA32(paH1, v11, oH1, 0,0,0);
    __builtin_amdgcn_s_setprio(0);
    // ---- issue V loads for t+1
    if (more){
      const unsigned short* vp = vp0 + (size_t)(kt+1)*512*32;
      vA = *(const uint4*)(vp);        vB = *(const uint4*)(vp + 16);
      vC = *(const uint4*)(vp + 1024); vD = *(const uint4*)(vp + 1040);
    }
  }

  float lfullL = lsumL + __shfl_xor(lsumL, 32, 64);
  float lfullH = lsumH + __shfl_xor(lsumH, 32, 64);
  if (hi == 0){
    lbuf[(size_t)(b*2048 + q0 + l5)*16      + s*8 + (hv*4 + w)] = lfullL;
    lbuf[(size_t)(b*2048 + q0 + 32 + l5)*16 + s*8 + (hv*4 + w)] = lfullH;
  }
  unsigned short* op = Op + (size_t)s * 4194304u;
#pragma unroll
  for (int nt=0; nt<2; ++nt){
#pragma unroll
    for (int r=0;r<16;++r){
      int qlocal = (r&3) + 8*(r>>2) + 4*hi;
      int d = hcho + nt*32 + l5;
      op[(size_t)(b*2048 + q0 + qlocal)*512 + d]      = bf16r(nt==0 ? oL0[r] : oL1[r]);
      op[(size_t)(b*2048 + q0 + 32 + qlocal)*512 + d] = bf16r(nt==0 ? oH0[r] : oH1[r]);
    }
  }
}

// ---------------- combine partials + divide + residual + LayerNorm0 -> bf16
__global__ __launch_bounds__(256) void combine_ln_kernel(
    const unsigned short* __restrict__ OpA, const unsigned short* __restrict__ OpB,
    const float* __restrict__ lbuf, const unsigned short* __restrict__ qb,
    const float* __restrict__ g, const float* __restrict__ be,
    unsigned short* __restrict__ Y)
{
  int row = blockIdx.x*4 + (threadIdx.x >> 6);
  int lane = threadIdx.x & 63;
  int h = lane >> 3;
  float lA = lbuf[(size_t)row*16 + h];
  float lB = lbuf[(size_t)row*16 + 8 + h];
  float inv = __builtin_amdgcn_rcpf(lA + lB);
  size_t base = (size_t)row*512 + lane*8;
  bf16x8 a  = *(const bf16x8*)&OpA[base];
  bf16x8 bb = *(const bf16x8*)&OpB[base];
  bf16x8 qv = *(const bf16x8*)&qb[base];
  float x0 = (bf2f((unsigned short)a[0]) + bf2f((unsigned short)bb[0]))*inv + bf2f((unsigned short)qv[0]);
  float x1 = (bf2f((unsigned short)a[1]) + bf2f((unsigned short)bb[1]))*inv + bf2f((unsigned short)qv[1]);
  float x2 = (bf2f((unsigned short)a[2]) + bf2f((unsigned short)bb[2]))*inv + bf2f((unsigned short)qv[2]);
  float x3 = (bf2f((unsigned short)a[3]) + bf2f((unsigned short)bb[3]))*inv + bf2f((unsigned short)qv[3]);
  float x4 = (bf2f((unsigned short)a[4]) + bf2f((unsigned short)bb[4]))*inv + bf2f((unsigned short)qv[4]);
  float x5 = (bf2f((unsigned short)a[5]) + bf2f((unsigned short)bb[5]))*inv + bf2f((unsigned short)qv[5]);
  float x6 = (bf2f((unsigned short)a[6]) + bf2f((unsigned short)bb[6]))*inv + bf2f((unsigned short)qv[6]);
  float x7 = (bf2f((unsigned short)a[7]) + bf2f((unsigned short)bb[7]))*inv + bf2f((unsigned short)qv[7]);
  float sm = ((x0+x1)+(x2+x3)) + ((x4+x5)+(x6+x7));
#pragma unroll
  for (int m=1; m<64; m<<=1) sm += __shfl_xor(sm, m, 64);
  float mean = sm * (1.0f/512.0f);
  float d0=x0-mean, d1=x1-mean, d2=x2-mean, d3=x3-mean;
  float d4=x4-mean, d5=x5-mean, d6=x6-mean, d7=x7-mean;
  float s2 = ((d0*d0+d1*d1)+(d2*d2+d3*d3)) + ((d4*d4+d5*d5)+(d6*d6+d7*d7));
#pragma unroll
  for (int m=1; m<64; m<<=1) s2 += __shfl_xor(s2, m, 64);
  float rstd = rsqrtf(s2*(1.0f/512.0f) + 1e-5f);
  const float* gp = g + lane*8; const float* bp = be + lane*8;
  float4 g0 = *(const float4*)gp, g1 = *(const float4*)(gp+4);
  float4 b0 = *(const float4*)bp, b1 = *(const float4*)(bp+4);
  uint4 yo;
  yo.x = bfpack2(d0*rstd*g0.x + b0.x, d1*rstd*g0.y + b0.y);
  yo.y = bfpack2(d2*rstd*g0.z + b0.z, d3*rstd*g0.w + b0.w);
  yo.z = bfpack2(d4*rstd*g1.x + b1.x, d5*rstd*g1.y + b1.y);
  yo.w = bfpack2(d6*rstd*g1.z + b1.z, d7*rstd*g1.w + b1.w);
  *(uint4*)&Y[base] = yo;
}

// ---------------- LayerNorm over 512, 4 rows/block (one per wave)
__global__ __launch_bounds__(256) void ln_kernel(
    const float* __restrict__ X, const float* __restrict__ g,
    const float* __restrict__ be, float* __restrict__ Y)
{
  int row = blockIdx.x*4 + (threadIdx.x >> 6);
  int lane = threadIdx.x & 63;
  const float* x = X + (size_t)row*512 + lane*8;
  float4 v0 = *(const float4*)x;
  float4 v1 = *(const float4*)(x + 4);
  float s = ((v0.x+v0.y)+(v0.z+v0.w)) + ((v1.x+v1.y)+(v1.z+v1.w));
#pragma unroll
  for (int m=1; m<64; m<<=1) s += __shfl_xor(s, m, 64);
  float mean = s * (1.0f/512.0f);
  float d0=v0.x-mean, d1=v0.y-mean, d2=v0.z-mean, d3=v0.w-mean;
  float d4=v1.x-mean, d5=v1.y-mean, d6=v1.z-mean, d7=v1.w-mean;
  float s2 = ((d0*d0+d1*d1)+(d2*d2+d3*d3)) + ((d4*d4+d5*d5)+(d6*d6+d7*d7));
#pragma unroll
  for (int m=1; m<64; m<<=1) s2 += __shfl_xor(s2, m, 64);
  float rstd = rsqrtf(s2*(1.0f/512.0f) + 1e-5f);
  const float* gp = g + lane*8; const float* bp = be + lane*8;
  float4 g0 = *(const float4*)gp, g1 = *(const float4*)(gp+4);
  float4 b0 = *(const float4*)bp, b1 = *(const float4*)(bp+4);
  float4 y0, y1;
  y0.x = d0*rstd*g0.x + b0.x; y0.y = d1*rstd*g0.y + b0.y;
  y0.z = d2*rstd*g0.z + b0.z; y0.w = d3*rstd*g0.w + b0.w;
  y1.x = d4*rstd*g1.x + b1.x; y1.y = d5*rstd*g1.y + b1.y;
  y1.z = d6*rstd*g1.z + b1.z; y1.w = d7*rstd*g1.w + b1.w;
  float* yp = Y + (size_t)row*512 + lane*8;
  *(float4*)yp = y0;
  *(float4*)(yp+4) = y1;
}

extern "C" void kernel_launch(void* const* d_in, const int* in_sizes, int n_in,
                              void* d_out, int out_size, void* d_ws, size_t ws_size,
                              hipStream_t stream) {
  const float* Q    = (const float*)d_in[0];
  const float* K    = (const float*)d_in[1];
  const int*   mask = (const int*)d_in[2];
  const float* temp = (const float*)d_in[3];
  const float* Wq = (const float*)d_in[4];  const float* bq = (const float*)d_in[5];
  const float* Wk = (const float*)d_in[6];  const float* bk = (const float*)d_in[7];
  const float* Wv = (const float*)d_in[8];  const float* bv = (const float*)d_in[9];
  const float* Wo = (const float*)d_in[10]; const float* bo = (const float*)d_in[11];
  const float* g0 = (const float*)d_in[12]; const float* b0 = (const float*)d_in[13];
  const float* g1 = (const float*)d_in[14]; const float* b1 = (const float*)d_in[15];
  float* out = (float*)d_out;
  (void)in_sizes; (void)n_in; (void)out_size; (void)ws_size;

  char* ws = (char*)d_ws;
  unsigned short* qbuf = (unsigned short*)(ws + 0);          // 8.4MB  q proj (bf16)
  unsigned short* kbuf = (unsigned short*)(ws + 8388608);    // 8.4MB  k proj (scaled)
  unsigned short* vtb  = (unsigned short*)(ws + 16777216);   // 8.4MB  v tile-major
  unsigned short* OpA  = (unsigned short*)(ws + 25165824);   // 2x 8.4MB bf16 partials
  unsigned short* WqT  = (unsigned short*)(ws + 41943040);   // 4 x 0.5MB
  unsigned short* WkT  = WqT + 262144;
  unsigned short* WvT  = WqT + 524288;
  unsigned short* WoT  = WqT + 786432;
  float* lbuf = (float*)(ws + 44040192);                     // 512KB per-(row,split,head) sums
  unsigned short* Olnf = (unsigned short*)(ws + 8388608);    // 8.4MB post-LN0 bf16 (alias kbuf)
  float* O2   = (float*)(ws + 25165824);                     // 16.8MB post-GEMM (alias partials)

  wt_kernel<<<dim3(8,8,4), 256, 0, stream>>>(Wq, Wk, Wv, Wo, WqT, WkT, WvT, WoT);
  qkv_kernel<<<dim3(64,4,3), 256, 0, stream>>>(Q, K, WqT, WkT, WvT, bq, bk, bv, temp,
                                               qbuf, kbuf, vtb);
  attn_kernel<<<512, 256, 0, stream>>>(qbuf, kbuf, vtb, mask, OpA, lbuf);
  combine_ln_kernel<<<2048, 256, 0, stream>>>(OpA, OpA + 4194304, lbuf, qbuf, g0, b0, Olnf);
  gemm_o_kernel<<<dim3(64,4), 256, 0, stream>>>(Olnf, WoT, bo, O2, Olnf);
  ln_kernel<<<2048, 256, 0, stream>>>(O2, g1, b1, out);
}